// Round 1
// 279.674 us; speedup vs baseline: 1.0325x; 1.0325x over previous
//
#include <hip/hip_runtime.h>
#include <math.h>

__global__ __launch_bounds__(256) void gs_fwd(
    const float* __restrict__ points,
    const float* __restrict__ quats,
    const float* __restrict__ scales,
    const float* __restrict__ colors,
    const float* __restrict__ opac,
    const float* __restrict__ E,      // extrinsic 4x4 row-major
    const float* __restrict__ I,      // intrinsic 4x4 row-major
    const int* __restrict__ p_fx,
    const int* __restrict__ p_fy,
    const int* __restrict__ p_w,
    const int* __restrict__ p_h,
    const int* __restrict__ p_tile,
    float* __restrict__ out,
    int N)
{
    // Staging buffer for the 16-float rows: stride 5 float4s (80 B) per
    // gaussian. 80 B stride => dword stride 20 => both the b128 writes
    // (addr = 20*t + 4q) and the b128 reads (addr = 20*(t/4) + 4*(t%4))
    // hit every bank exactly 8 times per wave instruction — the uniform
    // minimum, i.e. conflict-free.
    __shared__ float4 lds4[256 * 5];

    const int tid = threadIdx.x;
    const int i = blockIdx.x * 256 + tid;

    if (i < N) {
        const float fx = (float)p_fx[0];
        const float fy = (float)p_fy[0];
        const float fw = (float)p_w[0];
        const float fh = (float)p_h[0];
        const float ftile = (float)p_tile[0];
        const float rtile = __builtin_amdgcn_rcpf(ftile);

        // tan(2*atan(a)/2) == a
        const float tanX = fw / (2.0f * fx);
        const float tanY = fh / (2.0f * fy);
        const int max_tx = (int)ceilf(fw * rtile) - 1;
        const int max_ty = (int)ceilf(fh * rtile) - 1;

        // ---- quaternion -> rotation (normalize via rsqrt) ----
        const float4 q = reinterpret_cast<const float4*>(quats)[i];
        const float rq = rsqrtf(q.x*q.x + q.y*q.y + q.z*q.z + q.w*q.w);
        const float qr = q.x * rq;
        const float qx = q.y * rq;
        const float qy = q.z * rq;
        const float qz = q.w * rq;

        const float r00 = 1.0f - 2.0f * (qy*qy + qz*qz);
        const float r01 = 2.0f * (qx*qy - qr*qz);
        const float r02 = 2.0f * (qx*qz + qr*qy);
        const float r10 = 2.0f * (qx*qy + qr*qz);
        const float r11 = 1.0f - 2.0f * (qx*qx + qz*qz);
        const float r12 = 2.0f * (qy*qz - qr*qx);
        const float r20 = 2.0f * (qx*qz - qr*qy);
        const float r21 = 2.0f * (qy*qz + qr*qx);
        const float r22 = 1.0f - 2.0f * (qx*qx + qy*qy);

        const float s0 = scales[3*i + 0];
        const float s1 = scales[3*i + 1];
        const float s2 = scales[3*i + 2];

        const float m00 = r00*s0, m01 = r01*s1, m02 = r02*s2;
        const float m10 = r10*s0, m11 = r11*s1, m12 = r12*s2;
        const float m20 = r20*s0, m21 = r21*s1, m22 = r22*s2;

        // cov3d = M @ M^T (symmetric)
        const float S00 = m00*m00 + m01*m01 + m02*m02;
        const float S01 = m00*m10 + m01*m11 + m02*m12;
        const float S02 = m00*m20 + m01*m21 + m02*m22;
        const float S11 = m10*m10 + m11*m11 + m12*m12;
        const float S12 = m10*m20 + m11*m21 + m12*m22;
        const float S22 = m20*m20 + m21*m21 + m22*m22;

        // ---- camera transform: pc = [p,1] @ E ----
        const float p0 = points[3*i + 0];
        const float p1 = points[3*i + 1];
        const float p2 = points[3*i + 2];
        const float pc0 = p0*E[0]  + p1*E[4]  + p2*E[8]  + E[12];
        const float pc1 = p0*E[1]  + p1*E[5]  + p2*E[9]  + E[13];
        const float pc2 = p0*E[2]  + p1*E[6]  + p2*E[10] + E[14];
        const float pc3 = p0*E[3]  + p1*E[7]  + p2*E[11] + E[15];

        const float zc = pc2;
        const bool  zmask = zc > 0.2f;
        const float z_safe = zmask ? zc : 1.0f;
        const float rz = __builtin_amdgcn_rcpf(z_safe);   // 1/z_safe (~1 ulp)

        const float limX = 1.3f * tanX;
        const float limY = 1.3f * tanY;
        const float xx = fminf(fmaxf(pc0 * rz, -limX), limX) * zc;
        const float yy = fminf(fmaxf(pc1 * rz, -limY), limY) * zc;

        const float j00 = fx * rz;
        const float j02 = -(fx * xx) * rz * rz;
        const float j11 = fy * rz;
        const float j12 = -(fy * yy) * rz * rz;

        // T = Wm @ J^T (columns; third column of J is zero)
        const float t00 = E[0]*j00 + E[2]*j02;
        const float t01 = E[4]*j00 + E[6]*j02;
        const float t02 = E[8]*j00 + E[10]*j02;
        const float t10 = E[1]*j11 + E[2]*j12;
        const float t11 = E[5]*j11 + E[6]*j12;
        const float t12 = E[9]*j11 + E[10]*j12;

        // C = T^T Sigma T (2x2)
        const float v00 = S00*t00 + S01*t01 + S02*t02;
        const float v01 = S01*t00 + S11*t01 + S12*t02;
        const float v02 = S02*t00 + S12*t01 + S22*t02;
        const float v10 = S00*t10 + S01*t11 + S02*t12;
        const float v11 = S01*t10 + S11*t11 + S12*t12;
        const float v12 = S02*t10 + S12*t11 + S22*t12;

        const float a = (t00*v00 + t01*v01 + t02*v02) + 0.3f;
        const float b = (t00*v10 + t01*v11 + t02*v12);
        const float c = (t10*v00 + t11*v01 + t12*v02);
        const float d = (t10*v10 + t11*v11 + t12*v12) + 0.3f;

        // ---- NDC: ndc = pc @ I ----
        const float n0 = pc0*I[0] + pc1*I[4] + pc2*I[8]  + pc3*I[12];
        const float n1 = pc0*I[1] + pc1*I[5] + pc2*I[9]  + pc3*I[13];
        const float n2 = pc0*I[2] + pc1*I[6] + pc2*I[10] + pc3*I[14];
        const float n3 = pc0*I[3] + pc1*I[7] + pc2*I[11] + pc3*I[15];

        const float w_safe = zmask ? n3 : 1.0f;
        const float rw = __builtin_amdgcn_rcpf(w_safe);
        const float nx = n0 * rw;
        const float ny = n1 * rw;
        const float nz = n2;

        const bool mask = (nz > 0.2f) && (nx < 1.3f) && (nx > -1.3f)
                                      && (ny < 1.3f) && (ny > -1.3f);
        const float fm = mask ? 1.0f : 0.0f;

        const float det = a*d - b*c;   // >= ~0.09 (PSD + 0.3 I), so rcp is safe
        const float det_safe = (fabsf(det) < 1e-12f) ? 1e-12f : det;
        const float rdet = __builtin_amdgcn_rcpf(det_safe);
        const float inv00 =  d * rdet;
        const float inv01 = -b * rdet;
        const float inv10 = -c * rdet;
        const float inv11 =  a * rdet;

        const float mid = 0.5f * (a + d);
        const float sq  = sqrtf(fmaxf(mid*mid - det, 0.1f));
        const float lmax = fmaxf(mid + sq, mid - sq);
        const float radius = ceilf(3.0f * sqrtf(fmaxf(lmax, 1e-6f)));

        const float px = ((nx + 1.0f) * fw - 1.0f) * 0.5f;
        const float py = ((ny + 1.0f) * fh - 1.0f) * 0.5f;

        int tlx = (int)((px - radius) * rtile);
        int tly = (int)((py - radius) * rtile);
        int brx = (int)((px + radius) * rtile);
        int bry = (int)((py + radius) * rtile);
        tlx = min(max(tlx, 0), max_tx);
        tly = min(max(tly, 0), max_ty);
        brx = min(max(brx, 0), max_tx);
        bry = min(max(bry, 0), max_ty);

        const int sx = max(brx + 1 - tlx, 1);
        const int sy = max(bry + 1 - tly, 1);
        const float tiles = mask ? (float)(sx * sy) : 0.0f;

        const float c0 = colors[3*i + 0];
        const float c1 = colors[3*i + 1];
        const float c2 = colors[3*i + 2];
        const float op = opac[i];

        // ---- stage the 16-float row in LDS (branchless: multiply by mask) ----
        lds4[tid*5 + 0] = make_float4(px*fm, py*fm, nz*fm, a*fm);
        lds4[tid*5 + 1] = make_float4(b*fm, c*fm, d*fm, inv00*fm);
        lds4[tid*5 + 2] = make_float4(inv01*fm, inv10*fm, inv11*fm, radius*fm);
        lds4[tid*5 + 3] = make_float4(c0*fm, c1*fm, c2*fm, op*fm);

        // ---- tail streams (already per-instruction coalesced dword streams) ----
        const size_t nb = (size_t)N;
        const size_t base = nb * 16;
        out[base + i]        = tiles;        // tiles_touched
        out[base + nb + i]   = (float)tlx;   // top_left row 0
        out[base + 2*nb + i] = (float)tly;   // top_left row 1
        out[base + 3*nb + i] = (float)brx;   // bottom_right row 0
        out[base + 4*nb + i] = (float)bry;   // bottom_right row 1
        out[base + 5*nb + i] = fm;           // mask
    }

    __syncthreads();

    // ---- fully-coalesced row store: block writes its contiguous 16 KB ----
    // Store k: lanes write float4 index base4 + k*256 + tid — consecutive
    // lanes hit consecutive 16 B => 1 KB per wave store instruction.
    const size_t base4 = (size_t)blockIdx.x * 1024;   // block's first float4
    const size_t lim4  = (size_t)N * 4;               // float_out is 4N float4s
    float4* __restrict__ orow = reinterpret_cast<float4*>(out);
    #pragma unroll
    for (int k = 0; k < 4; ++k) {
        const size_t idx4 = base4 + (size_t)(k*256 + tid);
        if (idx4 < lim4) {
            const int gl = k*64 + (tid >> 2);   // gaussian-local index in block
            const int cc = tid & 3;             // which float4 of that gaussian
            orow[idx4] = lds4[gl*5 + cc];
        }
    }
}

extern "C" void kernel_launch(void* const* d_in, const int* in_sizes, int n_in,
                              void* d_out, int out_size, void* d_ws, size_t ws_size,
                              hipStream_t stream) {
    const float* points = (const float*)d_in[0];
    const float* quats  = (const float*)d_in[1];
    const float* scales = (const float*)d_in[2];
    const float* colors = (const float*)d_in[3];
    const float* opac   = (const float*)d_in[4];
    const float* E      = (const float*)d_in[5];
    const float* I      = (const float*)d_in[6];
    const int* p_fx   = (const int*)d_in[7];
    const int* p_fy   = (const int*)d_in[8];
    const int* p_w    = (const int*)d_in[9];
    const int* p_h    = (const int*)d_in[10];
    const int* p_tile = (const int*)d_in[11];

    const int N = in_sizes[4];   // opacity has exactly N elements
    const int block = 256;
    const int grid = (N + block - 1) / block;
    gs_fwd<<<grid, block, 0, stream>>>(points, quats, scales, colors, opac,
                                       E, I, p_fx, p_fy, p_w, p_h, p_tile,
                                       (float*)d_out, N);
}

// Round 2
// 276.316 us; speedup vs baseline: 1.0450x; 1.0122x over previous
//
#include <hip/hip_runtime.h>
#include <math.h>

__global__ __launch_bounds__(256) void gs_fwd(
    const float* __restrict__ points,
    const float* __restrict__ quats,
    const float* __restrict__ scales,
    const float* __restrict__ colors,
    const float* __restrict__ opac,
    const float* __restrict__ E,      // extrinsic 4x4 row-major
    const float* __restrict__ I,      // intrinsic 4x4 row-major
    const int* __restrict__ p_fx,
    const int* __restrict__ p_fy,
    const int* __restrict__ p_w,
    const int* __restrict__ p_h,
    const int* __restrict__ p_tile,
    float* __restrict__ out,
    int N)
{
    // Input staging: dense cooperative loads of the three float3 streams.
    // Each wave instruction covers 1024 contiguous bytes (vs the naive
    // stride-3 pattern where every cache line is touched by 3 different
    // instructions -> 3x request amplification).
    __shared__ float ldsp[768];
    __shared__ float ldss[768];
    __shared__ float ldsc[768];
    // Output staging: stride 5 float4s (80 B) per gaussian => both the b128
    // writes (dword addr 20*t + 4q) and reads (20*(t/4) + 4*(t%4)) hit every
    // bank exactly 8x per wave instruction — uniform minimum, conflict-free.
    __shared__ float4 lds4[256 * 5];

    const int tid = threadIdx.x;
    const int i = blockIdx.x * 256 + tid;

    // ---- dense staging of points/scales/colors ----
    {
        const size_t gbase = (size_t)blockIdx.x * 768;
        const size_t lim = (size_t)N * 3;
        #pragma unroll
        for (int k = 0; k < 3; ++k) {
            const int li = k * 256 + tid;
            const size_t g = gbase + (size_t)li;
            float vp = 0.0f, vs = 0.0f, vc = 0.0f;
            if (g < lim) {              // uniform for all but the last block
                vp = points[g];
                vs = scales[g];
                vc = colors[g];
            }
            ldsp[li] = vp;
            ldss[li] = vs;
            ldsc[li] = vc;
        }
    }
    __syncthreads();

    if (i < N) {
        const float fx = (float)p_fx[0];
        const float fy = (float)p_fy[0];
        const float fw = (float)p_w[0];
        const float fh = (float)p_h[0];
        const float ftile = (float)p_tile[0];
        const float rtile = __builtin_amdgcn_rcpf(ftile);

        // tan(2*atan(a)/2) == a
        const float tanX = fw / (2.0f * fx);
        const float tanY = fh / (2.0f * fy);
        const int max_tx = (int)ceilf(fw * rtile) - 1;
        const int max_ty = (int)ceilf(fh * rtile) - 1;

        // ---- quaternion -> rotation (normalize via rsqrt) ----
        const float4 q = reinterpret_cast<const float4*>(quats)[i];
        const float rq = rsqrtf(q.x*q.x + q.y*q.y + q.z*q.z + q.w*q.w);
        const float qr = q.x * rq;
        const float qx = q.y * rq;
        const float qy = q.z * rq;
        const float qz = q.w * rq;

        const float r00 = 1.0f - 2.0f * (qy*qy + qz*qz);
        const float r01 = 2.0f * (qx*qy - qr*qz);
        const float r02 = 2.0f * (qx*qz + qr*qy);
        const float r10 = 2.0f * (qx*qy + qr*qz);
        const float r11 = 1.0f - 2.0f * (qx*qx + qz*qz);
        const float r12 = 2.0f * (qy*qz - qr*qx);
        const float r20 = 2.0f * (qx*qz - qr*qy);
        const float r21 = 2.0f * (qy*qz + qr*qx);
        const float r22 = 1.0f - 2.0f * (qx*qx + qy*qy);

        const float s0 = ldss[3*tid + 0];
        const float s1 = ldss[3*tid + 1];
        const float s2 = ldss[3*tid + 2];

        const float m00 = r00*s0, m01 = r01*s1, m02 = r02*s2;
        const float m10 = r10*s0, m11 = r11*s1, m12 = r12*s2;
        const float m20 = r20*s0, m21 = r21*s1, m22 = r22*s2;

        // cov3d = M @ M^T (symmetric)
        const float S00 = m00*m00 + m01*m01 + m02*m02;
        const float S01 = m00*m10 + m01*m11 + m02*m12;
        const float S02 = m00*m20 + m01*m21 + m02*m22;
        const float S11 = m10*m10 + m11*m11 + m12*m12;
        const float S12 = m10*m20 + m11*m21 + m12*m22;
        const float S22 = m20*m20 + m21*m21 + m22*m22;

        // ---- camera transform: pc = [p,1] @ E ----
        const float p0 = ldsp[3*tid + 0];
        const float p1 = ldsp[3*tid + 1];
        const float p2 = ldsp[3*tid + 2];
        const float pc0 = p0*E[0]  + p1*E[4]  + p2*E[8]  + E[12];
        const float pc1 = p0*E[1]  + p1*E[5]  + p2*E[9]  + E[13];
        const float pc2 = p0*E[2]  + p1*E[6]  + p2*E[10] + E[14];
        const float pc3 = p0*E[3]  + p1*E[7]  + p2*E[11] + E[15];

        const float zc = pc2;
        const bool  zmask = zc > 0.2f;
        const float z_safe = zmask ? zc : 1.0f;
        const float rz = __builtin_amdgcn_rcpf(z_safe);   // 1/z_safe (~1 ulp)

        const float limX = 1.3f * tanX;
        const float limY = 1.3f * tanY;
        const float xx = fminf(fmaxf(pc0 * rz, -limX), limX) * zc;
        const float yy = fminf(fmaxf(pc1 * rz, -limY), limY) * zc;

        const float j00 = fx * rz;
        const float j02 = -(fx * xx) * rz * rz;
        const float j11 = fy * rz;
        const float j12 = -(fy * yy) * rz * rz;

        // T = Wm @ J^T (columns; third column of J is zero)
        const float t00 = E[0]*j00 + E[2]*j02;
        const float t01 = E[4]*j00 + E[6]*j02;
        const float t02 = E[8]*j00 + E[10]*j02;
        const float t10 = E[1]*j11 + E[2]*j12;
        const float t11 = E[5]*j11 + E[6]*j12;
        const float t12 = E[9]*j11 + E[10]*j12;

        // C = T^T Sigma T (2x2)
        const float v00 = S00*t00 + S01*t01 + S02*t02;
        const float v01 = S01*t00 + S11*t01 + S12*t02;
        const float v02 = S02*t00 + S12*t01 + S22*t02;
        const float v10 = S00*t10 + S01*t11 + S02*t12;
        const float v11 = S01*t10 + S11*t11 + S12*t12;
        const float v12 = S02*t10 + S12*t11 + S22*t12;

        const float a = (t00*v00 + t01*v01 + t02*v02) + 0.3f;
        const float b = (t00*v10 + t01*v11 + t02*v12);
        const float c = (t10*v00 + t11*v01 + t12*v02);
        const float d = (t10*v10 + t11*v11 + t12*v12) + 0.3f;

        // ---- NDC: ndc = pc @ I ----
        const float n0 = pc0*I[0] + pc1*I[4] + pc2*I[8]  + pc3*I[12];
        const float n1 = pc0*I[1] + pc1*I[5] + pc2*I[9]  + pc3*I[13];
        const float n2 = pc0*I[2] + pc1*I[6] + pc2*I[10] + pc3*I[14];
        const float n3 = pc0*I[3] + pc1*I[7] + pc2*I[11] + pc3*I[15];

        const float w_safe = zmask ? n3 : 1.0f;
        const float rw = __builtin_amdgcn_rcpf(w_safe);
        const float nx = n0 * rw;
        const float ny = n1 * rw;
        const float nz = n2;

        const bool mask = (nz > 0.2f) && (nx < 1.3f) && (nx > -1.3f)
                                      && (ny < 1.3f) && (ny > -1.3f);
        const float fm = mask ? 1.0f : 0.0f;

        const float det = a*d - b*c;   // >= ~0.09 (PSD + 0.3 I), so rcp is safe
        const float det_safe = (fabsf(det) < 1e-12f) ? 1e-12f : det;
        const float rdet = __builtin_amdgcn_rcpf(det_safe);
        const float inv00 =  d * rdet;
        const float inv01 = -b * rdet;
        const float inv10 = -c * rdet;
        const float inv11 =  a * rdet;

        const float mid = 0.5f * (a + d);
        const float sq  = sqrtf(fmaxf(mid*mid - det, 0.1f));
        const float lmax = fmaxf(mid + sq, mid - sq);
        const float radius = ceilf(3.0f * sqrtf(fmaxf(lmax, 1e-6f)));

        const float px = ((nx + 1.0f) * fw - 1.0f) * 0.5f;
        const float py = ((ny + 1.0f) * fh - 1.0f) * 0.5f;

        int tlx = (int)((px - radius) * rtile);
        int tly = (int)((py - radius) * rtile);
        int brx = (int)((px + radius) * rtile);
        int bry = (int)((py + radius) * rtile);
        tlx = min(max(tlx, 0), max_tx);
        tly = min(max(tly, 0), max_ty);
        brx = min(max(brx, 0), max_tx);
        bry = min(max(bry, 0), max_ty);

        const int sx = max(brx + 1 - tlx, 1);
        const int sy = max(bry + 1 - tly, 1);
        const float tiles = mask ? (float)(sx * sy) : 0.0f;

        const float c0 = ldsc[3*tid + 0];
        const float c1 = ldsc[3*tid + 1];
        const float c2 = ldsc[3*tid + 2];
        const float op = opac[i];

        // ---- stage the 16-float row in LDS (branchless: multiply by mask) ----
        lds4[tid*5 + 0] = make_float4(px*fm, py*fm, nz*fm, a*fm);
        lds4[tid*5 + 1] = make_float4(b*fm, c*fm, d*fm, inv00*fm);
        lds4[tid*5 + 2] = make_float4(inv01*fm, inv10*fm, inv11*fm, radius*fm);
        lds4[tid*5 + 3] = make_float4(c0*fm, c1*fm, c2*fm, op*fm);

        // ---- tail streams (per-instruction coalesced dword streams) ----
        const size_t nb = (size_t)N;
        const size_t base = nb * 16;
        out[base + i]        = tiles;        // tiles_touched
        out[base + nb + i]   = (float)tlx;   // top_left row 0
        out[base + 2*nb + i] = (float)tly;   // top_left row 1
        out[base + 3*nb + i] = (float)brx;   // bottom_right row 0
        out[base + 4*nb + i] = (float)bry;   // bottom_right row 1
        out[base + 5*nb + i] = fm;           // mask
    }

    __syncthreads();

    // ---- fully-coalesced row store: block writes its contiguous 16 KB ----
    // Store k: lanes write float4 index base4 + k*256 + tid — consecutive
    // lanes hit consecutive 16 B => 1 KB per wave store instruction.
    const size_t base4 = (size_t)blockIdx.x * 1024;   // block's first float4
    const size_t lim4  = (size_t)N * 4;               // float_out is 4N float4s
    float4* __restrict__ orow = reinterpret_cast<float4*>(out);
    #pragma unroll
    for (int k = 0; k < 4; ++k) {
        const size_t idx4 = base4 + (size_t)(k*256 + tid);
        if (idx4 < lim4) {
            const int gl = k*64 + (tid >> 2);   // gaussian-local index in block
            const int cc = tid & 3;             // which float4 of that gaussian
            orow[idx4] = lds4[gl*5 + cc];
        }
    }
}

extern "C" void kernel_launch(void* const* d_in, const int* in_sizes, int n_in,
                              void* d_out, int out_size, void* d_ws, size_t ws_size,
                              hipStream_t stream) {
    const float* points = (const float*)d_in[0];
    const float* quats  = (const float*)d_in[1];
    const float* scales = (const float*)d_in[2];
    const float* colors = (const float*)d_in[3];
    const float* opac   = (const float*)d_in[4];
    const float* E      = (const float*)d_in[5];
    const float* I      = (const float*)d_in[6];
    const int* p_fx   = (const int*)d_in[7];
    const int* p_fy   = (const int*)d_in[8];
    const int* p_w    = (const int*)d_in[9];
    const int* p_h    = (const int*)d_in[10];
    const int* p_tile = (const int*)d_in[11];

    const int N = in_sizes[4];   // opacity has exactly N elements
    const int block = 256;
    const int grid = (N + block - 1) / block;
    gs_fwd<<<grid, block, 0, stream>>>(points, quats, scales, colors, opac,
                                       E, I, p_fx, p_fy, p_w, p_h, p_tile,
                                       (float*)d_out, N);
}